// Round 8
// baseline (363.984 us; speedup 1.0000x reference)
//
#include <hip/hip_runtime.h>
#include <hip/hip_bf16.h>

#define IN_DIM 256
#define HID 128
#define CCH 2
#define RR 5
#define LL 2
#define NCLS 16

typedef __attribute__((ext_vector_type(8))) short short8;
typedef __attribute__((ext_vector_type(4))) short short4_;
typedef __attribute__((ext_vector_type(4))) float floatx4;

__device__ __forceinline__ unsigned short f2bf(float f) {
    unsigned int u = __float_as_uint(f);
    unsigned int r = (u + 0x7FFFu + ((u >> 16) & 1u)) >> 16;   // RN-even
    return (unsigned short)r;
}

// ---------------- fused: Filt softmax + weight convert/transpose ----------------
__global__ void cvt_weights(const float* __restrict__ Wc, const float* __restrict__ W1,
                            const float* __restrict__ gt_w,
                            unsigned short* __restrict__ WcT, unsigned short* __restrict__ W1T,
                            float* __restrict__ filt) {
    int i = blockIdx.x * 256 + threadIdx.x;
    if (blockIdx.x == 0 && threadIdx.x < LL * CCH) {
        const float* g = gt_w + threadIdx.x * RR;
        float m = -1e30f;
        for (int r = 0; r < RR; ++r) m = fmaxf(m, g[r]);
        float e[RR], s = 0.f;
        for (int r = 0; r < RR; ++r) { e[r] = __expf(g[r] - m); s += e[r]; }
        for (int r = 0; r < RR; ++r) filt[threadIdx.x * RR + r] = e[r] / s;
    }
    if (i < CCH * HID * IN_DIM) {            // 65536: WcT[c][d][k]
        int c = i >> 15;
        int rem = i & 32767;
        int d = rem >> 8;
        int k = rem & 255;
        WcT[i] = f2bf(Wc[((size_t)c * IN_DIM + k) * HID + d]);
    }
    if (i < HID * IN_DIM) {                  // 32768: W1T[d][k]
        int d = i >> 8;
        int k = i & 255;
        W1T[i] = f2bf(W1[(size_t)k * HID + d]);
    }
}

// ---------------- Projection via MFMA -> interleaved H0[n][m], m=c*128+d ----------------
// mt-split x4: block (blk>>2) covers 64 nodes, (blk&3) selects 4 of 16 output tiles.
__global__ __launch_bounds__(256) void proj_mfma(const float* __restrict__ h,
                                                 const unsigned short* __restrict__ WcT,
                                                 unsigned short* __restrict__ H0, int N) {
    int t = threadIdx.x;
    int wv = t >> 6, l = t & 63;
    int l15 = l & 15, lq = l >> 4;
    int mtb = (blockIdx.x & 3) << 2;                 // 0,4,8,12
    int node = (blockIdx.x >> 2) * 64 + wv * 16 + l15;
    int nclamp = node < N ? node : N - 1;

    short8 bfrag[8];
    const float* hrow = h + (size_t)nclamp * IN_DIM;
#pragma unroll
    for (int kk = 0; kk < 8; ++kk) {
        int k0 = kk * 32 + lq * 8;
        floatx4 f0 = *(const floatx4*)(hrow + k0);
        floatx4 f1 = *(const floatx4*)(hrow + k0 + 4);
        short8 b;
        b[0] = (short)f2bf(f0[0]); b[1] = (short)f2bf(f0[1]);
        b[2] = (short)f2bf(f0[2]); b[3] = (short)f2bf(f0[3]);
        b[4] = (short)f2bf(f1[0]); b[5] = (short)f2bf(f1[1]);
        b[6] = (short)f2bf(f1[2]); b[7] = (short)f2bf(f1[3]);
        bfrag[kk] = b;
    }

#pragma unroll
    for (int mt0 = 0; mt0 < 4; ++mt0) {
        int mt = mtb + mt0;
        floatx4 acc = {0.f, 0.f, 0.f, 0.f};
        const unsigned short* arow = WcT + (size_t)(mt * 16 + l15) * IN_DIM;
#pragma unroll
        for (int kk = 0; kk < 8; ++kk) {
            short8 a = *(const short8*)(arow + kk * 32 + lq * 8);
            acc = __builtin_amdgcn_mfma_f32_16x16x32_bf16(a, bfrag[kk], acc, 0, 0, 0);
        }
        if (node < N) {
            int m0 = mt * 16 + lq * 4;          // 0..255 over (c,d), interleaved
            short4_ st;
            st[0] = (short)f2bf(acc[0]); st[1] = (short)f2bf(acc[1]);
            st[2] = (short)f2bf(acc[2]); st[3] = (short)f2bf(acc[3]);
            *(short4_*)(H0 + (size_t)node * (CCH * HID) + m0) = st;
        }
    }
}

// ---------------- CSR build ----------------
__global__ void count_kernel(const int* __restrict__ dst, int* __restrict__ counts, int E) {
    for (int e = blockIdx.x * blockDim.x + threadIdx.x; e < E; e += gridDim.x * blockDim.x)
        atomicAdd(&counts[dst[e]], 1);
}

__global__ void scanA_kernel(const int* __restrict__ counts, int* __restrict__ partials, int n) {
    __shared__ int s[256];
    int t = threadIdx.x;
    int i = blockIdx.x * 256 + t;
    int v = (i < n) ? counts[i] : 0;
    s[t] = v;
    __syncthreads();
    for (int off = 1; off < 256; off <<= 1) {
        int tv = (t >= off) ? s[t - off] : 0;
        __syncthreads();
        s[t] += tv;
        __syncthreads();
    }
    if (t == 255) partials[blockIdx.x] = s[255];
}

__global__ void scanB_kernel(const int* __restrict__ partials, int* __restrict__ chunk_off, int nchunk) {
    __shared__ int s[256];
    int t = threadIdx.x;
    int v = (t < nchunk) ? partials[t] : 0;
    s[t] = v;
    __syncthreads();
    for (int off = 1; off < 256; off <<= 1) {
        int tv = (t >= off) ? s[t - off] : 0;
        __syncthreads();
        s[t] += tv;
        __syncthreads();
    }
    if (t < nchunk) chunk_off[t] = s[t] - v;   // exclusive
}

__global__ void scanC_kernel(const int* __restrict__ counts, const int* __restrict__ chunk_off,
                             int* __restrict__ offsets, int* __restrict__ cursor, int n) {
    __shared__ int s[256];
    int t = threadIdx.x;
    int i = blockIdx.x * 256 + t;
    int v = (i < n) ? counts[i] : 0;
    s[t] = v;
    __syncthreads();
    for (int off = 1; off < 256; off <<= 1) {
        int tv = (t >= off) ? s[t - off] : 0;
        __syncthreads();
        s[t] += tv;
        __syncthreads();
    }
    if (i < n) {
        int incl = chunk_off[blockIdx.x] + s[t];
        offsets[i + 1] = incl;
        cursor[i] = incl - v;
    }
    if (i == 0) offsets[0] = 0;
}

__global__ void fill_kernel(const int* __restrict__ src, const int* __restrict__ dst,
                            const int* __restrict__ etype, int* __restrict__ cursor,
                            int2* __restrict__ epack, int E) {
    for (int e = blockIdx.x * blockDim.x + threadIdx.x; e < E; e += gridDim.x * blockDim.x) {
        int d = dst[e];
        int p = atomicAdd(&cursor[d], 1);
        epack[p] = make_int2(src[e], etype[e]);
    }
}

// ---------------- Aggregation: 1 node/block, 8 edge-groups x 32 lanes x 16B ----------------
__global__ __launch_bounds__(256) void agg_kernel(const uint4* __restrict__ Hin,
                                                  uint4* __restrict__ Hout,
                                                  const int* __restrict__ offs,
                                                  const int2* __restrict__ epack,
                                                  const float* __restrict__ filt, int N) {
    int node = blockIdx.x;
    int t = threadIdx.x;
    int g = t >> 5;            // edge group 0..7
    int lane32 = t & 31;       // 16B chunk within the 512B row
    int c = lane32 >> 4;       // channel: chunks 0-15 -> c=0, 16-31 -> c=1
    float f0 = filt[c * RR + 0], f1 = filt[c * RR + 1], f2 = filt[c * RR + 2];
    float f3 = filt[c * RR + 3], f4 = filt[c * RR + 4];

    int e0 = offs[node], e1 = offs[node + 1];
    float acc[8];
#pragma unroll
    for (int r = 0; r < 8; ++r) acc[r] = 0.f;
    float deg = 0.f;

    for (int j = e0 + g; j < e1; j += 8) {
        int2 pc = epack[j];
        uint4 v = Hin[(size_t)pc.x * 32 + lane32];
        int et = pc.y;
        float w = (et == 0) ? f0 : (et == 1) ? f1 : (et == 2) ? f2 : (et == 3) ? f3 : f4;
        deg += w;
        acc[0] += w * __uint_as_float(v.x << 16);
        acc[1] += w * __uint_as_float(v.x & 0xFFFF0000u);
        acc[2] += w * __uint_as_float(v.y << 16);
        acc[3] += w * __uint_as_float(v.y & 0xFFFF0000u);
        acc[4] += w * __uint_as_float(v.z << 16);
        acc[5] += w * __uint_as_float(v.z & 0xFFFF0000u);
        acc[6] += w * __uint_as_float(v.w << 16);
        acc[7] += w * __uint_as_float(v.w & 0xFFFF0000u);
    }

#pragma unroll
    for (int r = 0; r < 8; ++r) acc[r] += __shfl_xor(acc[r], 32);
    deg += __shfl_xor(deg, 32);

    __shared__ float sacc[3][8][33];
    __shared__ float sdeg[3][33];
    int wv = t >> 6;
    bool lowhalf = (t & 63) < 32;
    if (wv > 0 && lowhalf) {
#pragma unroll
        for (int r = 0; r < 8; ++r) sacc[wv - 1][r][lane32] = acc[r];
        sdeg[wv - 1][lane32] = deg;
    }
    __syncthreads();
    if (wv == 0 && lowhalf) {
#pragma unroll
        for (int k = 0; k < 3; ++k) {
#pragma unroll
            for (int r = 0; r < 8; ++r) acc[r] += sacc[k][r][lane32];
            deg += sdeg[k][lane32];
        }
        float inv = 1.f / deg;
        uint4 o;
        o.x = (unsigned int)f2bf(acc[0] * inv) | ((unsigned int)f2bf(acc[1] * inv) << 16);
        o.y = (unsigned int)f2bf(acc[2] * inv) | ((unsigned int)f2bf(acc[3] * inv) << 16);
        o.z = (unsigned int)f2bf(acc[4] * inv) | ((unsigned int)f2bf(acc[5] * inv) << 16);
        o.w = (unsigned int)f2bf(acc[6] * inv) | ((unsigned int)f2bf(acc[7] * inv) << 16);
        Hout[(size_t)node * 32 + lane32] = o;
    }
}

// ---------------- MLP1 via MFMA on gathered interleaved rows ----------------
__global__ __launch_bounds__(256) void mlp1_mfma(const unsigned short* __restrict__ H2,
                                                 const int* __restrict__ cat,
                                                 const unsigned short* __restrict__ W1T,
                                                 const float* __restrict__ b1,
                                                 float* __restrict__ hidden, int NCAT) {
    int t = threadIdx.x;
    int wv = t >> 6, l = t & 63;
    int l15 = l & 15, lq = l >> 4;
    int i = blockIdx.x * 64 + wv * 16 + l15;
    int iclamp = i < NCAT ? i : NCAT - 1;
    int node = cat[iclamp];

    short8 bfrag[8];
    const unsigned short* xrow = H2 + (size_t)node * (CCH * HID);
#pragma unroll
    for (int kk = 0; kk < 8; ++kk)
        bfrag[kk] = *(const short8*)(xrow + kk * 32 + lq * 8);

#pragma unroll
    for (int mt = 0; mt < 8; ++mt) {
        floatx4 acc = {0.f, 0.f, 0.f, 0.f};
        const unsigned short* arow = W1T + (size_t)(mt * 16 + l15) * (CCH * HID);
#pragma unroll
        for (int kk = 0; kk < 8; ++kk) {
            short8 a = *(const short8*)(arow + kk * 32 + lq * 8);
            acc = __builtin_amdgcn_mfma_f32_16x16x32_bf16(a, bfrag[kk], acc, 0, 0, 0);
        }
        if (i < NCAT) {
            int d0 = mt * 16 + lq * 4;
            floatx4 o;
#pragma unroll
            for (int r = 0; r < 4; ++r) o[r] = fmaxf(acc[r] + b1[d0 + r], 0.f);
            *(floatx4*)(hidden + (size_t)i * HID + d0) = o;
        }
    }
}

// ---------------- MLP2 ----------------
__global__ void mlp2_kernel(const float* __restrict__ hidden, const float* __restrict__ W2,
                            const float* __restrict__ b2, float* __restrict__ out, int NCAT) {
    int idx = blockIdx.x * 256 + threadIdx.x;
    int i = idx >> 4, cls = idx & 15;
    if (i >= NCAT) return;
    const float* hrow = hidden + (size_t)i * HID;
    float acc = b2[cls];
#pragma unroll 8
    for (int j = 0; j < HID; ++j) acc += hrow[j] * W2[j * NCLS + cls];
    out[idx] = acc;
}

extern "C" void kernel_launch(void* const* d_in, const int* in_sizes, int n_in,
                              void* d_out, int out_size, void* d_ws, size_t ws_size,
                              hipStream_t stream) {
    const float* h    = (const float*)d_in[0];
    const int* src    = (const int*)d_in[1];
    const int* dst    = (const int*)d_in[2];
    const int* etype  = (const int*)d_in[3];
    const int* cat    = (const int*)d_in[4];
    const float* gt_w = (const float*)d_in[5];
    const float* Wc   = (const float*)d_in[6];
    const float* W1   = (const float*)d_in[7];
    const float* b1   = (const float*)d_in[8];
    const float* W2   = (const float*)d_in[9];
    const float* b2   = (const float*)d_in[10];
    float* out = (float*)d_out;

    const int N = in_sizes[0] / IN_DIM;   // 50000
    const int E = in_sizes[1];            // 500000
    const int NCAT = in_sizes[4];         // 10000
    const int NCHUNK = (N + 255) / 256;

    char* p = (char*)d_ws;
    auto alloc = [&](size_t bytes) {
        char* q = p;
        p += (bytes + 255) & ~(size_t)255;
        return q;
    };
    unsigned short* HA   = (unsigned short*)alloc((size_t)N * CCH * HID * 2);
    unsigned short* HB   = (unsigned short*)alloc((size_t)N * CCH * HID * 2);
    unsigned short* WcT  = (unsigned short*)alloc((size_t)CCH * HID * IN_DIM * 2);
    unsigned short* W1T  = (unsigned short*)alloc((size_t)HID * CCH * HID * 2);
    float* hidden        = (float*)alloc((size_t)NCAT * HID * 4);
    int*   counts        = (int*)alloc((size_t)N * 4);
    int*   offsets       = (int*)alloc((size_t)(N + 1) * 4);
    int*   cursor        = (int*)alloc((size_t)N * 4);
    int*   partials      = (int*)alloc((size_t)NCHUNK * 4);
    int*   chunk_off     = (int*)alloc((size_t)NCHUNK * 4);
    int2*  epack         = (int2*)alloc((size_t)E * 8);
    float* filt          = (float*)alloc((size_t)LL * CCH * RR * 4);

    hipMemsetAsync(counts, 0, (size_t)N * 4, stream);

    cvt_weights<<<(CCH * HID * IN_DIM + 255) / 256, 256, 0, stream>>>(Wc, W1, gt_w, WcT, W1T, filt);
    proj_mfma<<<((N + 63) / 64) * 4, 256, 0, stream>>>(h, WcT, HA, N);

    count_kernel<<<512, 256, 0, stream>>>(dst, counts, E);
    scanA_kernel<<<NCHUNK, 256, 0, stream>>>(counts, partials, N);
    scanB_kernel<<<1, 256, 0, stream>>>(partials, chunk_off, NCHUNK);
    scanC_kernel<<<NCHUNK, 256, 0, stream>>>(counts, chunk_off, offsets, cursor, N);
    fill_kernel<<<512, 256, 0, stream>>>(src, dst, etype, cursor, epack, E);

    agg_kernel<<<N, 256, 0, stream>>>((const uint4*)HA, (uint4*)HB,
                                      offsets, epack, filt, N);
    agg_kernel<<<N, 256, 0, stream>>>((const uint4*)HB, (uint4*)HA,
                                      offsets, epack, filt + CCH * RR, N);

    mlp1_mfma<<<(NCAT + 63) / 64, 256, 0, stream>>>(HA, cat, W1T, b1, hidden, NCAT);
    mlp2_kernel<<<(NCAT * NCLS + 255) / 256, 256, 0, stream>>>(hidden, W2, b2, out, NCAT);
}

// Round 9
// 321.138 us; speedup vs baseline: 1.1334x; 1.1334x over previous
//
#include <hip/hip_runtime.h>
#include <hip/hip_bf16.h>

#define IN_DIM 256
#define HID 128
#define CCH 2
#define RR 5
#define LL 2
#define NCLS 16

typedef __attribute__((ext_vector_type(8))) short short8;
typedef __attribute__((ext_vector_type(4))) short short4_;
typedef __attribute__((ext_vector_type(4))) float floatx4;

__device__ __forceinline__ unsigned short f2bf(float f) {
    unsigned int u = __float_as_uint(f);
    unsigned int r = (u + 0x7FFFu + ((u >> 16) & 1u)) >> 16;   // RN-even
    return (unsigned short)r;
}

// ---------------- fused: Filt softmax + weight convert/transpose ----------------
__global__ void cvt_weights(const float* __restrict__ Wc, const float* __restrict__ W1,
                            const float* __restrict__ gt_w,
                            unsigned short* __restrict__ WcT, unsigned short* __restrict__ W1T,
                            float* __restrict__ filt) {
    int i = blockIdx.x * 256 + threadIdx.x;
    if (blockIdx.x == 0 && threadIdx.x < LL * CCH) {
        const float* g = gt_w + threadIdx.x * RR;
        float m = -1e30f;
        for (int r = 0; r < RR; ++r) m = fmaxf(m, g[r]);
        float e[RR], s = 0.f;
        for (int r = 0; r < RR; ++r) { e[r] = __expf(g[r] - m); s += e[r]; }
        for (int r = 0; r < RR; ++r) filt[threadIdx.x * RR + r] = e[r] / s;
    }
    if (i < CCH * HID * IN_DIM) {            // 65536: WcT[c][d][k]
        int c = i >> 15;
        int rem = i & 32767;
        int d = rem >> 8;
        int k = rem & 255;
        WcT[i] = f2bf(Wc[((size_t)c * IN_DIM + k) * HID + d]);
    }
    if (i < HID * IN_DIM) {                  // 32768: W1T[d][k]
        int d = i >> 8;
        int k = i & 255;
        W1T[i] = f2bf(W1[(size_t)k * HID + d]);
    }
}

// ---------------- Projection: LDS-staged B, register A, 4 mt/wave ----------------
// Block: 64 nodes x full M=256. B tile staged coalesced fp32 -> bf16 swizzled LDS.
__global__ __launch_bounds__(256, 2) void proj_mfma(const float* __restrict__ h,
                                                    const unsigned short* __restrict__ WcT,
                                                    unsigned short* __restrict__ H0, int N) {
    __shared__ unsigned short Bl[64 * 256];   // 32 KB, row r at shorts r*256, 16B chunk cs
    int t = threadIdx.x;
    int wv = t >> 6, l = t & 63;
    int l15 = l & 15, lq = l >> 4;
    int n0 = blockIdx.x * 64;

    // ---- stage B: 64 rows x 256 k fp32 -> bf16, swizzled chunk = c ^ ((r&7)<<2)
#pragma unroll
    for (int i = 0; i < 16; ++i) {
        int fi = t * 4 + i * 1024;           // float index within 64x256 tile
        int r = fi >> 8;                     // row 0..63
        int k = fi & 255;
        int node = n0 + r;
        const float* src = h + (size_t)(node < N ? node : N - 1) * IN_DIM + k;
        floatx4 f = *(const floatx4*)src;
        short4_ s4;
        s4[0] = (short)f2bf(f[0]); s4[1] = (short)f2bf(f[1]);
        s4[2] = (short)f2bf(f[2]); s4[3] = (short)f2bf(f[3]);
        int c = k >> 3;                      // 16B chunk 0..31
        int half = (k >> 2) & 1;
        int cs = c ^ ((r & 7) << 2);
        *(short4_*)(&Bl[r * 256 + cs * 8 + half * 4]) = s4;
    }
    __syncthreads();

    floatx4 acc[4][4];
#pragma unroll
    for (int m = 0; m < 4; ++m)
#pragma unroll
        for (int n = 0; n < 4; ++n) acc[m][n] = (floatx4){0.f, 0.f, 0.f, 0.f};

#pragma unroll
    for (int kh = 0; kh < 2; ++kh) {
        // A fragments for this K-half: wave's 4 mt tiles
        short8 a[4][4];
#pragma unroll
        for (int mt0 = 0; mt0 < 4; ++mt0) {
            const unsigned short* arow = WcT + (size_t)((wv * 4 + mt0) * 16 + l15) * IN_DIM;
#pragma unroll
            for (int kk = 0; kk < 4; ++kk)
                a[mt0][kk] = *(const short8*)(arow + (kh * 4 + kk) * 32 + lq * 8);
        }
#pragma unroll
        for (int nf = 0; nf < 4; ++nf) {
            int r = nf * 16 + l15;
            short8 b[4];
#pragma unroll
            for (int kk = 0; kk < 4; ++kk) {
                int c = (kh * 4 + kk) * 4 + lq;
                int cs = c ^ ((r & 7) << 2);
                b[kk] = *(const short8*)(&Bl[r * 256 + cs * 8]);
            }
#pragma unroll
            for (int mt0 = 0; mt0 < 4; ++mt0)
#pragma unroll
                for (int kk = 0; kk < 4; ++kk)
                    acc[mt0][nf] = __builtin_amdgcn_mfma_f32_16x16x32_bf16(a[mt0][kk], b[kk],
                                                                           acc[mt0][nf], 0, 0, 0);
        }
    }

#pragma unroll
    for (int mt0 = 0; mt0 < 4; ++mt0) {
        int m0 = (wv * 4 + mt0) * 16 + lq * 4;   // 0..255 over (c,d), interleaved
#pragma unroll
        for (int nf = 0; nf < 4; ++nf) {
            int node = n0 + nf * 16 + l15;
            if (node < N) {
                short4_ st;
                st[0] = (short)f2bf(acc[mt0][nf][0]); st[1] = (short)f2bf(acc[mt0][nf][1]);
                st[2] = (short)f2bf(acc[mt0][nf][2]); st[3] = (short)f2bf(acc[mt0][nf][3]);
                *(short4_*)(H0 + (size_t)node * (CCH * HID) + m0) = st;
            }
        }
    }
}

// ---------------- CSR build ----------------
__global__ void count_kernel(const int* __restrict__ dst, int* __restrict__ counts, int E) {
    for (int e = blockIdx.x * blockDim.x + threadIdx.x; e < E; e += gridDim.x * blockDim.x)
        atomicAdd(&counts[dst[e]], 1);
}

__global__ void scanA_kernel(const int* __restrict__ counts, int* __restrict__ partials, int n) {
    __shared__ int s[256];
    int t = threadIdx.x;
    int i = blockIdx.x * 256 + t;
    int v = (i < n) ? counts[i] : 0;
    s[t] = v;
    __syncthreads();
    for (int off = 1; off < 256; off <<= 1) {
        int tv = (t >= off) ? s[t - off] : 0;
        __syncthreads();
        s[t] += tv;
        __syncthreads();
    }
    if (t == 255) partials[blockIdx.x] = s[255];
}

__global__ void scanB_kernel(const int* __restrict__ partials, int* __restrict__ chunk_off, int nchunk) {
    __shared__ int s[256];
    int t = threadIdx.x;
    int v = (t < nchunk) ? partials[t] : 0;
    s[t] = v;
    __syncthreads();
    for (int off = 1; off < 256; off <<= 1) {
        int tv = (t >= off) ? s[t - off] : 0;
        __syncthreads();
        s[t] += tv;
        __syncthreads();
    }
    if (t < nchunk) chunk_off[t] = s[t] - v;   // exclusive
}

__global__ void scanC_kernel(const int* __restrict__ counts, const int* __restrict__ chunk_off,
                             int* __restrict__ offsets, int* __restrict__ cursor, int n) {
    __shared__ int s[256];
    int t = threadIdx.x;
    int i = blockIdx.x * 256 + t;
    int v = (i < n) ? counts[i] : 0;
    s[t] = v;
    __syncthreads();
    for (int off = 1; off < 256; off <<= 1) {
        int tv = (t >= off) ? s[t - off] : 0;
        __syncthreads();
        s[t] += tv;
        __syncthreads();
    }
    if (i < n) {
        int incl = chunk_off[blockIdx.x] + s[t];
        offsets[i + 1] = incl;
        cursor[i] = incl - v;
    }
    if (i == 0) offsets[0] = 0;
}

__global__ void fill_kernel(const int* __restrict__ src, const int* __restrict__ dst,
                            const int* __restrict__ etype, int* __restrict__ cursor,
                            int2* __restrict__ epack, int E) {
    for (int e = blockIdx.x * blockDim.x + threadIdx.x; e < E; e += gridDim.x * blockDim.x) {
        int d = dst[e];
        int p = atomicAdd(&cursor[d], 1);
        epack[p] = make_int2(src[e], etype[e]);
    }
}

// ---------------- Aggregation: 1 node/block, 8 edge-groups x 32 lanes x 16B ----------------
__global__ __launch_bounds__(256) void agg_kernel(const uint4* __restrict__ Hin,
                                                  uint4* __restrict__ Hout,
                                                  const int* __restrict__ offs,
                                                  const int2* __restrict__ epack,
                                                  const float* __restrict__ filt, int N) {
    int node = blockIdx.x;
    int t = threadIdx.x;
    int g = t >> 5;            // edge group 0..7
    int lane32 = t & 31;       // 16B chunk within the 512B row
    int c = lane32 >> 4;       // channel: chunks 0-15 -> c=0, 16-31 -> c=1
    float f0 = filt[c * RR + 0], f1 = filt[c * RR + 1], f2 = filt[c * RR + 2];
    float f3 = filt[c * RR + 3], f4 = filt[c * RR + 4];

    int e0 = offs[node], e1 = offs[node + 1];
    float acc[8];
#pragma unroll
    for (int r = 0; r < 8; ++r) acc[r] = 0.f;
    float deg = 0.f;

    for (int j = e0 + g; j < e1; j += 8) {
        int2 pc = epack[j];
        uint4 v = Hin[(size_t)pc.x * 32 + lane32];
        int et = pc.y;
        float w = (et == 0) ? f0 : (et == 1) ? f1 : (et == 2) ? f2 : (et == 3) ? f3 : f4;
        deg += w;
        acc[0] += w * __uint_as_float(v.x << 16);
        acc[1] += w * __uint_as_float(v.x & 0xFFFF0000u);
        acc[2] += w * __uint_as_float(v.y << 16);
        acc[3] += w * __uint_as_float(v.y & 0xFFFF0000u);
        acc[4] += w * __uint_as_float(v.z << 16);
        acc[5] += w * __uint_as_float(v.z & 0xFFFF0000u);
        acc[6] += w * __uint_as_float(v.w << 16);
        acc[7] += w * __uint_as_float(v.w & 0xFFFF0000u);
    }

#pragma unroll
    for (int r = 0; r < 8; ++r) acc[r] += __shfl_xor(acc[r], 32);
    deg += __shfl_xor(deg, 32);

    __shared__ float sacc[3][8][33];
    __shared__ float sdeg[3][33];
    int wv = t >> 6;
    bool lowhalf = (t & 63) < 32;
    if (wv > 0 && lowhalf) {
#pragma unroll
        for (int r = 0; r < 8; ++r) sacc[wv - 1][r][lane32] = acc[r];
        sdeg[wv - 1][lane32] = deg;
    }
    __syncthreads();
    if (wv == 0 && lowhalf) {
#pragma unroll
        for (int k = 0; k < 3; ++k) {
#pragma unroll
            for (int r = 0; r < 8; ++r) acc[r] += sacc[k][r][lane32];
            deg += sdeg[k][lane32];
        }
        float inv = 1.f / deg;
        uint4 o;
        o.x = (unsigned int)f2bf(acc[0] * inv) | ((unsigned int)f2bf(acc[1] * inv) << 16);
        o.y = (unsigned int)f2bf(acc[2] * inv) | ((unsigned int)f2bf(acc[3] * inv) << 16);
        o.z = (unsigned int)f2bf(acc[4] * inv) | ((unsigned int)f2bf(acc[5] * inv) << 16);
        o.w = (unsigned int)f2bf(acc[6] * inv) | ((unsigned int)f2bf(acc[7] * inv) << 16);
        Hout[(size_t)node * 32 + lane32] = o;
    }
}

// ---------------- MLP1 via MFMA on gathered interleaved rows ----------------
__global__ __launch_bounds__(256) void mlp1_mfma(const unsigned short* __restrict__ H2,
                                                 const int* __restrict__ cat,
                                                 const unsigned short* __restrict__ W1T,
                                                 const float* __restrict__ b1,
                                                 float* __restrict__ hidden, int NCAT) {
    int t = threadIdx.x;
    int wv = t >> 6, l = t & 63;
    int l15 = l & 15, lq = l >> 4;
    int i = blockIdx.x * 64 + wv * 16 + l15;
    int iclamp = i < NCAT ? i : NCAT - 1;
    int node = cat[iclamp];

    short8 bfrag[8];
    const unsigned short* xrow = H2 + (size_t)node * (CCH * HID);
#pragma unroll
    for (int kk = 0; kk < 8; ++kk)
        bfrag[kk] = *(const short8*)(xrow + kk * 32 + lq * 8);

#pragma unroll
    for (int mt = 0; mt < 8; ++mt) {
        floatx4 acc = {0.f, 0.f, 0.f, 0.f};
        const unsigned short* arow = W1T + (size_t)(mt * 16 + l15) * (CCH * HID);
#pragma unroll
        for (int kk = 0; kk < 8; ++kk) {
            short8 a = *(const short8*)(arow + kk * 32 + lq * 8);
            acc = __builtin_amdgcn_mfma_f32_16x16x32_bf16(a, bfrag[kk], acc, 0, 0, 0);
        }
        if (i < NCAT) {
            int d0 = mt * 16 + lq * 4;
            floatx4 o;
#pragma unroll
            for (int r = 0; r < 4; ++r) o[r] = fmaxf(acc[r] + b1[d0 + r], 0.f);
            *(floatx4*)(hidden + (size_t)i * HID + d0) = o;
        }
    }
}

// ---------------- MLP2 ----------------
__global__ void mlp2_kernel(const float* __restrict__ hidden, const float* __restrict__ W2,
                            const float* __restrict__ b2, float* __restrict__ out, int NCAT) {
    int idx = blockIdx.x * 256 + threadIdx.x;
    int i = idx >> 4, cls = idx & 15;
    if (i >= NCAT) return;
    const float* hrow = hidden + (size_t)i * HID;
    float acc = b2[cls];
#pragma unroll 8
    for (int j = 0; j < HID; ++j) acc += hrow[j] * W2[j * NCLS + cls];
    out[idx] = acc;
}

extern "C" void kernel_launch(void* const* d_in, const int* in_sizes, int n_in,
                              void* d_out, int out_size, void* d_ws, size_t ws_size,
                              hipStream_t stream) {
    const float* h    = (const float*)d_in[0];
    const int* src    = (const int*)d_in[1];
    const int* dst    = (const int*)d_in[2];
    const int* etype  = (const int*)d_in[3];
    const int* cat    = (const int*)d_in[4];
    const float* gt_w = (const float*)d_in[5];
    const float* Wc   = (const float*)d_in[6];
    const float* W1   = (const float*)d_in[7];
    const float* b1   = (const float*)d_in[8];
    const float* W2   = (const float*)d_in[9];
    const float* b2   = (const float*)d_in[10];
    float* out = (float*)d_out;

    const int N = in_sizes[0] / IN_DIM;   // 50000
    const int E = in_sizes[1];            // 500000
    const int NCAT = in_sizes[4];         // 10000
    const int NCHUNK = (N + 255) / 256;

    char* p = (char*)d_ws;
    auto alloc = [&](size_t bytes) {
        char* q = p;
        p += (bytes + 255) & ~(size_t)255;
        return q;
    };
    unsigned short* HA   = (unsigned short*)alloc((size_t)N * CCH * HID * 2);
    unsigned short* HB   = (unsigned short*)alloc((size_t)N * CCH * HID * 2);
    unsigned short* WcT  = (unsigned short*)alloc((size_t)CCH * HID * IN_DIM * 2);
    unsigned short* W1T  = (unsigned short*)alloc((size_t)HID * CCH * HID * 2);
    float* hidden        = (float*)alloc((size_t)NCAT * HID * 4);
    int*   counts        = (int*)alloc((size_t)N * 4);
    int*   offsets       = (int*)alloc((size_t)(N + 1) * 4);
    int*   cursor        = (int*)alloc((size_t)N * 4);
    int*   partials      = (int*)alloc((size_t)NCHUNK * 4);
    int*   chunk_off     = (int*)alloc((size_t)NCHUNK * 4);
    int2*  epack         = (int2*)alloc((size_t)E * 8);
    float* filt          = (float*)alloc((size_t)LL * CCH * RR * 4);

    hipMemsetAsync(counts, 0, (size_t)N * 4, stream);

    cvt_weights<<<(CCH * HID * IN_DIM + 255) / 256, 256, 0, stream>>>(Wc, W1, gt_w, WcT, W1T, filt);
    proj_mfma<<<(N + 63) / 64, 256, 0, stream>>>(h, WcT, HA, N);

    count_kernel<<<512, 256, 0, stream>>>(dst, counts, E);
    scanA_kernel<<<NCHUNK, 256, 0, stream>>>(counts, partials, N);
    scanB_kernel<<<1, 256, 0, stream>>>(partials, chunk_off, NCHUNK);
    scanC_kernel<<<NCHUNK, 256, 0, stream>>>(counts, chunk_off, offsets, cursor, N);
    fill_kernel<<<512, 256, 0, stream>>>(src, dst, etype, cursor, epack, E);

    agg_kernel<<<N, 256, 0, stream>>>((const uint4*)HA, (uint4*)HB,
                                      offsets, epack, filt, N);
    agg_kernel<<<N, 256, 0, stream>>>((const uint4*)HB, (uint4*)HA,
                                      offsets, epack, filt + CCH * RR, N);

    mlp1_mfma<<<(NCAT + 63) / 64, 256, 0, stream>>>(HA, cat, W1T, b1, hidden, NCAT);
    mlp2_kernel<<<(NCAT * NCLS + 255) / 256, 256, 0, stream>>>(hidden, W2, b2, out, NCAT);
}

// Round 10
// 296.714 us; speedup vs baseline: 1.2267x; 1.0823x over previous
//
#include <hip/hip_runtime.h>
#include <hip/hip_bf16.h>

#define IN_DIM 256
#define HID 128
#define CCH 2
#define RR 5
#define LL 2
#define NCLS 16

typedef __attribute__((ext_vector_type(8))) short short8;
typedef __attribute__((ext_vector_type(4))) short short4_;
typedef __attribute__((ext_vector_type(4))) float floatx4;

__device__ __forceinline__ unsigned short f2bf(float f) {
    unsigned int u = __float_as_uint(f);
    unsigned int r = (u + 0x7FFFu + ((u >> 16) & 1u)) >> 16;   // RN-even
    return (unsigned short)r;
}

// ---------------- fused: Filt softmax + weight convert/transpose ----------------
__global__ void cvt_weights(const float* __restrict__ Wc, const float* __restrict__ W1,
                            const float* __restrict__ gt_w,
                            unsigned short* __restrict__ WcT, unsigned short* __restrict__ W1T,
                            float* __restrict__ filt) {
    int i = blockIdx.x * 256 + threadIdx.x;
    if (blockIdx.x == 0 && threadIdx.x < LL * CCH) {
        const float* g = gt_w + threadIdx.x * RR;
        float m = -1e30f;
        for (int r = 0; r < RR; ++r) m = fmaxf(m, g[r]);
        float e[RR], s = 0.f;
        for (int r = 0; r < RR; ++r) { e[r] = __expf(g[r] - m); s += e[r]; }
        for (int r = 0; r < RR; ++r) filt[threadIdx.x * RR + r] = e[r] / s;
    }
    if (i < CCH * HID * IN_DIM) {            // 65536: WcT[c][d][k]
        int c = i >> 15;
        int rem = i & 32767;
        int d = rem >> 8;
        int k = rem & 255;
        WcT[i] = f2bf(Wc[((size_t)c * IN_DIM + k) * HID + d]);
    }
    if (i < HID * IN_DIM) {                  // 32768: W1T[d][k]
        int d = i >> 8;
        int k = i & 255;
        W1T[i] = f2bf(W1[(size_t)k * HID + d]);
    }
}

// ---------------- Projection: LDS-staged B, register A, 4 mt/wave ----------------
__global__ __launch_bounds__(256, 2) void proj_mfma(const float* __restrict__ h,
                                                    const unsigned short* __restrict__ WcT,
                                                    unsigned short* __restrict__ H0, int N) {
    __shared__ unsigned short Bl[64 * 256];   // 32 KB
    int t = threadIdx.x;
    int wv = t >> 6, l = t & 63;
    int l15 = l & 15, lq = l >> 4;
    int n0 = blockIdx.x * 64;

#pragma unroll
    for (int i = 0; i < 16; ++i) {
        int fi = t * 4 + i * 1024;
        int r = fi >> 8;
        int k = fi & 255;
        int node = n0 + r;
        const float* src = h + (size_t)(node < N ? node : N - 1) * IN_DIM + k;
        floatx4 f = *(const floatx4*)src;
        short4_ s4;
        s4[0] = (short)f2bf(f[0]); s4[1] = (short)f2bf(f[1]);
        s4[2] = (short)f2bf(f[2]); s4[3] = (short)f2bf(f[3]);
        int c = k >> 3;
        int half = (k >> 2) & 1;
        int cs = c ^ ((r & 7) << 2);
        *(short4_*)(&Bl[r * 256 + cs * 8 + half * 4]) = s4;
    }
    __syncthreads();

    floatx4 acc[4][4];
#pragma unroll
    for (int m = 0; m < 4; ++m)
#pragma unroll
        for (int n = 0; n < 4; ++n) acc[m][n] = (floatx4){0.f, 0.f, 0.f, 0.f};

#pragma unroll
    for (int kh = 0; kh < 2; ++kh) {
        short8 a[4][4];
#pragma unroll
        for (int mt0 = 0; mt0 < 4; ++mt0) {
            const unsigned short* arow = WcT + (size_t)((wv * 4 + mt0) * 16 + l15) * IN_DIM;
#pragma unroll
            for (int kk = 0; kk < 4; ++kk)
                a[mt0][kk] = *(const short8*)(arow + (kh * 4 + kk) * 32 + lq * 8);
        }
#pragma unroll
        for (int nf = 0; nf < 4; ++nf) {
            int r = nf * 16 + l15;
            short8 b[4];
#pragma unroll
            for (int kk = 0; kk < 4; ++kk) {
                int c = (kh * 4 + kk) * 4 + lq;
                int cs = c ^ ((r & 7) << 2);
                b[kk] = *(const short8*)(&Bl[r * 256 + cs * 8]);
            }
#pragma unroll
            for (int mt0 = 0; mt0 < 4; ++mt0)
#pragma unroll
                for (int kk = 0; kk < 4; ++kk)
                    acc[mt0][nf] = __builtin_amdgcn_mfma_f32_16x16x32_bf16(a[mt0][kk], b[kk],
                                                                           acc[mt0][nf], 0, 0, 0);
        }
    }

#pragma unroll
    for (int mt0 = 0; mt0 < 4; ++mt0) {
        int m0 = (wv * 4 + mt0) * 16 + lq * 4;
#pragma unroll
        for (int nf = 0; nf < 4; ++nf) {
            int node = n0 + nf * 16 + l15;
            if (node < N) {
                short4_ st;
                st[0] = (short)f2bf(acc[mt0][nf][0]); st[1] = (short)f2bf(acc[mt0][nf][1]);
                st[2] = (short)f2bf(acc[mt0][nf][2]); st[3] = (short)f2bf(acc[mt0][nf][3]);
                *(short4_*)(H0 + (size_t)node * (CCH * HID) + m0) = st;
            }
        }
    }
}

// ---------------- CSR build ----------------
__global__ void count_kernel(const int* __restrict__ dst, int* __restrict__ counts, int E) {
    for (int e = blockIdx.x * blockDim.x + threadIdx.x; e < E; e += gridDim.x * blockDim.x)
        atomicAdd(&counts[dst[e]], 1);
}

__global__ void scanA_kernel(const int* __restrict__ counts, int* __restrict__ partials, int n) {
    __shared__ int s[256];
    int t = threadIdx.x;
    int i = blockIdx.x * 256 + t;
    int v = (i < n) ? counts[i] : 0;
    s[t] = v;
    __syncthreads();
    for (int off = 1; off < 256; off <<= 1) {
        int tv = (t >= off) ? s[t - off] : 0;
        __syncthreads();
        s[t] += tv;
        __syncthreads();
    }
    if (t == 255) partials[blockIdx.x] = s[255];
}

__global__ void scanB_kernel(const int* __restrict__ partials, int* __restrict__ chunk_off, int nchunk) {
    __shared__ int s[256];
    int t = threadIdx.x;
    int v = (t < nchunk) ? partials[t] : 0;
    s[t] = v;
    __syncthreads();
    for (int off = 1; off < 256; off <<= 1) {
        int tv = (t >= off) ? s[t - off] : 0;
        __syncthreads();
        s[t] += tv;
        __syncthreads();
    }
    if (t < nchunk) chunk_off[t] = s[t] - v;   // exclusive
}

__global__ void scanC_kernel(const int* __restrict__ counts, const int* __restrict__ chunk_off,
                             int* __restrict__ offsets, int* __restrict__ cursor, int n) {
    __shared__ int s[256];
    int t = threadIdx.x;
    int i = blockIdx.x * 256 + t;
    int v = (i < n) ? counts[i] : 0;
    s[t] = v;
    __syncthreads();
    for (int off = 1; off < 256; off <<= 1) {
        int tv = (t >= off) ? s[t - off] : 0;
        __syncthreads();
        s[t] += tv;
        __syncthreads();
    }
    if (i < n) {
        int incl = chunk_off[blockIdx.x] + s[t];
        offsets[i + 1] = incl;
        cursor[i] = incl - v;
    }
    if (i == 0) offsets[0] = 0;
}

__global__ void fill_kernel(const int* __restrict__ src, const int* __restrict__ dst,
                            const int* __restrict__ etype, int* __restrict__ cursor,
                            int2* __restrict__ epack, int E) {
    for (int e = blockIdx.x * blockDim.x + threadIdx.x; e < E; e += gridDim.x * blockDim.x) {
        int d = dst[e];
        int p = atomicAdd(&cursor[d], 1);
        epack[p] = make_int2(src[e], etype[e]);
    }
}

// ---------------- Aggregation: 8 nodes/block, one 32-lane group per node ----------------
// No reductions: a group reads full 512B rows (32 x 16B) and owns its node outright.
__global__ __launch_bounds__(256) void agg_kernel(const uint4* __restrict__ Hin,
                                                  uint4* __restrict__ Hout,
                                                  const int* __restrict__ offs,
                                                  const int2* __restrict__ epack,
                                                  const float* __restrict__ filt, int N) {
    int t = threadIdx.x;
    int g = t >> 5;            // node slot 0..7
    int lane32 = t & 31;       // 16B chunk within 512B row
    int node = blockIdx.x * 8 + g;
    if (node >= N) return;
    int c = lane32 >> 4;       // channel
    float f0 = filt[c * RR + 0], f1 = filt[c * RR + 1], f2 = filt[c * RR + 2];
    float f3 = filt[c * RR + 3], f4 = filt[c * RR + 4];

    int e0 = offs[node], e1 = offs[node + 1];   // e1 > e0 (self-edge guaranteed)
    float acc[8];
#pragma unroll
    for (int r = 0; r < 8; ++r) acc[r] = 0.f;
    float deg = 0.f;

    // 1-deep software pipeline over this node's edges
    int2 pc = epack[e0];
    uint4 v = Hin[(size_t)pc.x * 32 + lane32];
    int et = pc.y;
    for (int j = e0 + 1; ; ++j) {
        uint4 vc = v;
        int etc = et;
        bool more = j < e1;
        if (more) {
            int2 pn = epack[j];
            v = Hin[(size_t)pn.x * 32 + lane32];
            et = pn.y;
        }
        float w = (etc == 0) ? f0 : (etc == 1) ? f1 : (etc == 2) ? f2 : (etc == 3) ? f3 : f4;
        deg += w;
        acc[0] += w * __uint_as_float(vc.x << 16);
        acc[1] += w * __uint_as_float(vc.x & 0xFFFF0000u);
        acc[2] += w * __uint_as_float(vc.y << 16);
        acc[3] += w * __uint_as_float(vc.y & 0xFFFF0000u);
        acc[4] += w * __uint_as_float(vc.z << 16);
        acc[5] += w * __uint_as_float(vc.z & 0xFFFF0000u);
        acc[6] += w * __uint_as_float(vc.w << 16);
        acc[7] += w * __uint_as_float(vc.w & 0xFFFF0000u);
        if (!more) break;
    }

    float inv = 1.f / deg;
    uint4 o;
    o.x = (unsigned int)f2bf(acc[0] * inv) | ((unsigned int)f2bf(acc[1] * inv) << 16);
    o.y = (unsigned int)f2bf(acc[2] * inv) | ((unsigned int)f2bf(acc[3] * inv) << 16);
    o.z = (unsigned int)f2bf(acc[4] * inv) | ((unsigned int)f2bf(acc[5] * inv) << 16);
    o.w = (unsigned int)f2bf(acc[6] * inv) | ((unsigned int)f2bf(acc[7] * inv) << 16);
    Hout[(size_t)node * 32 + lane32] = o;
}

// ---------------- MLP1 via MFMA on gathered interleaved rows ----------------
__global__ __launch_bounds__(256) void mlp1_mfma(const unsigned short* __restrict__ H2,
                                                 const int* __restrict__ cat,
                                                 const unsigned short* __restrict__ W1T,
                                                 const float* __restrict__ b1,
                                                 float* __restrict__ hidden, int NCAT) {
    int t = threadIdx.x;
    int wv = t >> 6, l = t & 63;
    int l15 = l & 15, lq = l >> 4;
    int i = blockIdx.x * 64 + wv * 16 + l15;
    int iclamp = i < NCAT ? i : NCAT - 1;
    int node = cat[iclamp];

    short8 bfrag[8];
    const unsigned short* xrow = H2 + (size_t)node * (CCH * HID);
#pragma unroll
    for (int kk = 0; kk < 8; ++kk)
        bfrag[kk] = *(const short8*)(xrow + kk * 32 + lq * 8);

#pragma unroll
    for (int mt = 0; mt < 8; ++mt) {
        floatx4 acc = {0.f, 0.f, 0.f, 0.f};
        const unsigned short* arow = W1T + (size_t)(mt * 16 + l15) * (CCH * HID);
#pragma unroll
        for (int kk = 0; kk < 8; ++kk) {
            short8 a = *(const short8*)(arow + kk * 32 + lq * 8);
            acc = __builtin_amdgcn_mfma_f32_16x16x32_bf16(a, bfrag[kk], acc, 0, 0, 0);
        }
        if (i < NCAT) {
            int d0 = mt * 16 + lq * 4;
            floatx4 o;
#pragma unroll
            for (int r = 0; r < 4; ++r) o[r] = fmaxf(acc[r] + b1[d0 + r], 0.f);
            *(floatx4*)(hidden + (size_t)i * HID + d0) = o;
        }
    }
}

// ---------------- MLP2 ----------------
__global__ void mlp2_kernel(const float* __restrict__ hidden, const float* __restrict__ W2,
                            const float* __restrict__ b2, float* __restrict__ out, int NCAT) {
    int idx = blockIdx.x * 256 + threadIdx.x;
    int i = idx >> 4, cls = idx & 15;
    if (i >= NCAT) return;
    const float* hrow = hidden + (size_t)i * HID;
    float acc = b2[cls];
#pragma unroll 8
    for (int j = 0; j < HID; ++j) acc += hrow[j] * W2[j * NCLS + cls];
    out[idx] = acc;
}

extern "C" void kernel_launch(void* const* d_in, const int* in_sizes, int n_in,
                              void* d_out, int out_size, void* d_ws, size_t ws_size,
                              hipStream_t stream) {
    const float* h    = (const float*)d_in[0];
    const int* src    = (const int*)d_in[1];
    const int* dst    = (const int*)d_in[2];
    const int* etype  = (const int*)d_in[3];
    const int* cat    = (const int*)d_in[4];
    const float* gt_w = (const float*)d_in[5];
    const float* Wc   = (const float*)d_in[6];
    const float* W1   = (const float*)d_in[7];
    const float* b1   = (const float*)d_in[8];
    const float* W2   = (const float*)d_in[9];
    const float* b2   = (const float*)d_in[10];
    float* out = (float*)d_out;

    const int N = in_sizes[0] / IN_DIM;   // 50000
    const int E = in_sizes[1];            // 500000
    const int NCAT = in_sizes[4];         // 10000
    const int NCHUNK = (N + 255) / 256;

    char* p = (char*)d_ws;
    auto alloc = [&](size_t bytes) {
        char* q = p;
        p += (bytes + 255) & ~(size_t)255;
        return q;
    };
    unsigned short* HA   = (unsigned short*)alloc((size_t)N * CCH * HID * 2);
    unsigned short* HB   = (unsigned short*)alloc((size_t)N * CCH * HID * 2);
    unsigned short* WcT  = (unsigned short*)alloc((size_t)CCH * HID * IN_DIM * 2);
    unsigned short* W1T  = (unsigned short*)alloc((size_t)HID * CCH * HID * 2);
    float* hidden        = (float*)alloc((size_t)NCAT * HID * 4);
    int*   counts        = (int*)alloc((size_t)N * 4);
    int*   offsets       = (int*)alloc((size_t)(N + 1) * 4);
    int*   cursor        = (int*)alloc((size_t)N * 4);
    int*   partials      = (int*)alloc((size_t)NCHUNK * 4);
    int*   chunk_off     = (int*)alloc((size_t)NCHUNK * 4);
    int2*  epack         = (int2*)alloc((size_t)E * 8);
    float* filt          = (float*)alloc((size_t)LL * CCH * RR * 4);

    hipMemsetAsync(counts, 0, (size_t)N * 4, stream);

    cvt_weights<<<(CCH * HID * IN_DIM + 255) / 256, 256, 0, stream>>>(Wc, W1, gt_w, WcT, W1T, filt);
    proj_mfma<<<(N + 63) / 64, 256, 0, stream>>>(h, WcT, HA, N);

    count_kernel<<<512, 256, 0, stream>>>(dst, counts, E);
    scanA_kernel<<<NCHUNK, 256, 0, stream>>>(counts, partials, N);
    scanB_kernel<<<1, 256, 0, stream>>>(partials, chunk_off, NCHUNK);
    scanC_kernel<<<NCHUNK, 256, 0, stream>>>(counts, chunk_off, offsets, cursor, N);
    fill_kernel<<<512, 256, 0, stream>>>(src, dst, etype, cursor, epack, E);

    agg_kernel<<<(N + 7) / 8, 256, 0, stream>>>((const uint4*)HA, (uint4*)HB,
                                                offsets, epack, filt, N);
    agg_kernel<<<(N + 7) / 8, 256, 0, stream>>>((const uint4*)HB, (uint4*)HA,
                                                offsets, epack, filt + CCH * RR, N);

    mlp1_mfma<<<(NCAT + 63) / 64, 256, 0, stream>>>(HA, cat, W1T, b1, hidden, NCAT);
    mlp2_kernel<<<(NCAT * NCLS + 255) / 256, 256, 0, stream>>>(hidden, W2, b2, out, NCAT);
}

// Round 11
// 290.628 us; speedup vs baseline: 1.2524x; 1.0209x over previous
//
#include <hip/hip_runtime.h>
#include <hip/hip_bf16.h>

#define IN_DIM 256
#define HID 128
#define CCH 2
#define RR 5
#define LL 2
#define NCLS 16

typedef __attribute__((ext_vector_type(8))) short short8;
typedef __attribute__((ext_vector_type(4))) short short4_;
typedef __attribute__((ext_vector_type(4))) float floatx4;

__device__ __forceinline__ unsigned short f2bf(float f) {
    unsigned int u = __float_as_uint(f);
    unsigned int r = (u + 0x7FFFu + ((u >> 16) & 1u)) >> 16;   // RN-even
    return (unsigned short)r;
}

// ---------------- fused: Filt softmax + weight convert/transpose ----------------
__global__ void cvt_weights(const float* __restrict__ Wc, const float* __restrict__ W1,
                            const float* __restrict__ gt_w,
                            unsigned short* __restrict__ WcT, unsigned short* __restrict__ W1T,
                            float* __restrict__ filt) {
    int i = blockIdx.x * 256 + threadIdx.x;
    if (blockIdx.x == 0 && threadIdx.x < LL * CCH) {
        const float* g = gt_w + threadIdx.x * RR;
        float m = -1e30f;
        for (int r = 0; r < RR; ++r) m = fmaxf(m, g[r]);
        float e[RR], s = 0.f;
        for (int r = 0; r < RR; ++r) { e[r] = __expf(g[r] - m); s += e[r]; }
        for (int r = 0; r < RR; ++r) filt[threadIdx.x * RR + r] = e[r] / s;
    }
    if (i < CCH * HID * IN_DIM) {            // 65536: WcT[c][d][k]
        int c = i >> 15;
        int rem = i & 32767;
        int d = rem >> 8;
        int k = rem & 255;
        WcT[i] = f2bf(Wc[((size_t)c * IN_DIM + k) * HID + d]);
    }
    if (i < HID * IN_DIM) {                  // 32768: W1T[d][k]
        int d = i >> 8;
        int k = i & 255;
        W1T[i] = f2bf(W1[(size_t)k * HID + d]);
    }
}

// ---------------- Projection: LDS-staged B, register A, 4 mt/wave ----------------
__global__ __launch_bounds__(256, 2) void proj_mfma(const float* __restrict__ h,
                                                    const unsigned short* __restrict__ WcT,
                                                    unsigned short* __restrict__ H0, int N) {
    __shared__ unsigned short Bl[64 * 256];   // 32 KB
    int t = threadIdx.x;
    int wv = t >> 6, l = t & 63;
    int l15 = l & 15, lq = l >> 4;
    int n0 = blockIdx.x * 64;

#pragma unroll
    for (int i = 0; i < 16; ++i) {
        int fi = t * 4 + i * 1024;
        int r = fi >> 8;
        int k = fi & 255;
        int node = n0 + r;
        const float* src = h + (size_t)(node < N ? node : N - 1) * IN_DIM + k;
        floatx4 f = *(const floatx4*)src;
        short4_ s4;
        s4[0] = (short)f2bf(f[0]); s4[1] = (short)f2bf(f[1]);
        s4[2] = (short)f2bf(f[2]); s4[3] = (short)f2bf(f[3]);
        int c = k >> 3;
        int half = (k >> 2) & 1;
        int cs = c ^ ((r & 7) << 2);
        *(short4_*)(&Bl[r * 256 + cs * 8 + half * 4]) = s4;
    }
    __syncthreads();

    floatx4 acc[4][4];
#pragma unroll
    for (int m = 0; m < 4; ++m)
#pragma unroll
        for (int n = 0; n < 4; ++n) acc[m][n] = (floatx4){0.f, 0.f, 0.f, 0.f};

#pragma unroll
    for (int kh = 0; kh < 2; ++kh) {
        short8 a[4][4];
#pragma unroll
        for (int mt0 = 0; mt0 < 4; ++mt0) {
            const unsigned short* arow = WcT + (size_t)((wv * 4 + mt0) * 16 + l15) * IN_DIM;
#pragma unroll
            for (int kk = 0; kk < 4; ++kk)
                a[mt0][kk] = *(const short8*)(arow + (kh * 4 + kk) * 32 + lq * 8);
        }
#pragma unroll
        for (int nf = 0; nf < 4; ++nf) {
            int r = nf * 16 + l15;
            short8 b[4];
#pragma unroll
            for (int kk = 0; kk < 4; ++kk) {
                int c = (kh * 4 + kk) * 4 + lq;
                int cs = c ^ ((r & 7) << 2);
                b[kk] = *(const short8*)(&Bl[r * 256 + cs * 8]);
            }
#pragma unroll
            for (int mt0 = 0; mt0 < 4; ++mt0)
#pragma unroll
                for (int kk = 0; kk < 4; ++kk)
                    acc[mt0][nf] = __builtin_amdgcn_mfma_f32_16x16x32_bf16(a[mt0][kk], b[kk],
                                                                           acc[mt0][nf], 0, 0, 0);
        }
    }

#pragma unroll
    for (int mt0 = 0; mt0 < 4; ++mt0) {
        int m0 = (wv * 4 + mt0) * 16 + lq * 4;
#pragma unroll
        for (int nf = 0; nf < 4; ++nf) {
            int node = n0 + nf * 16 + l15;
            if (node < N) {
                short4_ st;
                st[0] = (short)f2bf(acc[mt0][nf][0]); st[1] = (short)f2bf(acc[mt0][nf][1]);
                st[2] = (short)f2bf(acc[mt0][nf][2]); st[3] = (short)f2bf(acc[mt0][nf][3]);
                *(short4_*)(H0 + (size_t)node * (CCH * HID) + m0) = st;
            }
        }
    }
}

// ---------------- CSR build ----------------
__global__ void count_kernel(const int* __restrict__ dst, int* __restrict__ counts, int E) {
    for (int e = blockIdx.x * blockDim.x + threadIdx.x; e < E; e += gridDim.x * blockDim.x)
        atomicAdd(&counts[dst[e]], 1);
}

__global__ void scanA_kernel(const int* __restrict__ counts, int* __restrict__ partials, int n) {
    __shared__ int s[256];
    int t = threadIdx.x;
    int i = blockIdx.x * 256 + t;
    int v = (i < n) ? counts[i] : 0;
    s[t] = v;
    __syncthreads();
    for (int off = 1; off < 256; off <<= 1) {
        int tv = (t >= off) ? s[t - off] : 0;
        __syncthreads();
        s[t] += tv;
        __syncthreads();
    }
    if (t == 255) partials[blockIdx.x] = s[255];
}

__global__ void scanB_kernel(const int* __restrict__ partials, int* __restrict__ chunk_off, int nchunk) {
    __shared__ int s[256];
    int t = threadIdx.x;
    int v = (t < nchunk) ? partials[t] : 0;
    s[t] = v;
    __syncthreads();
    for (int off = 1; off < 256; off <<= 1) {
        int tv = (t >= off) ? s[t - off] : 0;
        __syncthreads();
        s[t] += tv;
        __syncthreads();
    }
    if (t < nchunk) chunk_off[t] = s[t] - v;   // exclusive
}

__global__ void scanC_kernel(const int* __restrict__ counts, const int* __restrict__ chunk_off,
                             int* __restrict__ offsets, int* __restrict__ cursor, int n) {
    __shared__ int s[256];
    int t = threadIdx.x;
    int i = blockIdx.x * 256 + t;
    int v = (i < n) ? counts[i] : 0;
    s[t] = v;
    __syncthreads();
    for (int off = 1; off < 256; off <<= 1) {
        int tv = (t >= off) ? s[t - off] : 0;
        __syncthreads();
        s[t] += tv;
        __syncthreads();
    }
    if (i < n) {
        int incl = chunk_off[blockIdx.x] + s[t];
        offsets[i + 1] = incl;
        cursor[i] = incl - v;
    }
    if (i == 0) offsets[0] = 0;
}

__global__ void fill_kernel(const int* __restrict__ src, const int* __restrict__ dst,
                            const int* __restrict__ etype, int* __restrict__ cursor,
                            int2* __restrict__ epack, int E) {
    for (int e = blockIdx.x * blockDim.x + threadIdx.x; e < E; e += gridDim.x * blockDim.x) {
        int d = dst[e];
        int p = atomicAdd(&cursor[d], 1);
        epack[p] = make_int2(src[e], etype[e]);
    }
}

// ---------------- Aggregation: 8 nodes/block, 32-lane group per node ----------------
// Edge list register-resident (lane i holds edge i); src/etype via shfl broadcast.
// Row loads have no dependent prefix and are issued 2 edges ahead.
#define GETSRC(dn, s_, e_) do {                                     \
    s_ = __shfl(ep.x, (dn) & 31, 32);                               \
    e_ = __shfl(ep.y, (dn) & 31, 32);                               \
    if ((dn) >= 32) { int2 _p = epack[e0 + (dn)]; s_ = _p.x; e_ = _p.y; } \
} while (0)

#define ACCUM(vv, ww) do {                                          \
    acc[0] += (ww) * __uint_as_float((vv).x << 16);                 \
    acc[1] += (ww) * __uint_as_float((vv).x & 0xFFFF0000u);         \
    acc[2] += (ww) * __uint_as_float((vv).y << 16);                 \
    acc[3] += (ww) * __uint_as_float((vv).y & 0xFFFF0000u);         \
    acc[4] += (ww) * __uint_as_float((vv).z << 16);                 \
    acc[5] += (ww) * __uint_as_float((vv).z & 0xFFFF0000u);         \
    acc[6] += (ww) * __uint_as_float((vv).w << 16);                 \
    acc[7] += (ww) * __uint_as_float((vv).w & 0xFFFF0000u);         \
} while (0)

__global__ __launch_bounds__(256) void agg_kernel(const uint4* __restrict__ Hin,
                                                  uint4* __restrict__ Hout,
                                                  const int* __restrict__ offs,
                                                  const int2* __restrict__ epack,
                                                  const float* __restrict__ filt, int N) {
    int t = threadIdx.x;
    int g = t >> 5;            // node slot 0..7
    int lane32 = t & 31;       // 16B chunk within 512B row
    int node = blockIdx.x * 8 + g;
    if (node >= N) return;
    int c = lane32 >> 4;       // channel
    float f0 = filt[c * RR + 0], f1 = filt[c * RR + 1], f2 = filt[c * RR + 2];
    float f3 = filt[c * RR + 3], f4 = filt[c * RR + 4];

    int e0 = offs[node], e1 = offs[node + 1];   // deg >= 1 (self-edge)
    int deg = e1 - e0;
    int2 ep = epack[e0 + (lane32 < deg ? lane32 : deg - 1)];   // lane i holds edge i

    float acc[8];
#pragma unroll
    for (int r = 0; r < 8; ++r) acc[r] = 0.f;
    float dw = 0.f;

    uint4 va, vb;
    int eta = 0, etb = 0;
    { int s; GETSRC(0, s, eta); va = Hin[(size_t)s * 32 + lane32]; }
    if (deg > 1) { int s; GETSRC(1, s, etb); vb = Hin[(size_t)s * 32 + lane32]; }
    else vb = va;

    int d = 0;
    for (;;) {
        {
            float w = (eta == 0) ? f0 : (eta == 1) ? f1 : (eta == 2) ? f2 : (eta == 3) ? f3 : f4;
            dw += w;
            ACCUM(va, w);
        }
        int dn = d + 2;
        if (dn < deg) { int s; GETSRC(dn, s, eta); va = Hin[(size_t)s * 32 + lane32]; }
        ++d; if (d >= deg) break;
        {
            float w = (etb == 0) ? f0 : (etb == 1) ? f1 : (etb == 2) ? f2 : (etb == 3) ? f3 : f4;
            dw += w;
            ACCUM(vb, w);
        }
        dn = d + 2;
        if (dn < deg) { int s; GETSRC(dn, s, etb); vb = Hin[(size_t)s * 32 + lane32]; }
        ++d; if (d >= deg) break;
    }

    float inv = 1.f / dw;
    uint4 o;
    o.x = (unsigned int)f2bf(acc[0] * inv) | ((unsigned int)f2bf(acc[1] * inv) << 16);
    o.y = (unsigned int)f2bf(acc[2] * inv) | ((unsigned int)f2bf(acc[3] * inv) << 16);
    o.z = (unsigned int)f2bf(acc[4] * inv) | ((unsigned int)f2bf(acc[5] * inv) << 16);
    o.w = (unsigned int)f2bf(acc[6] * inv) | ((unsigned int)f2bf(acc[7] * inv) << 16);
    Hout[(size_t)node * 32 + lane32] = o;
}

// ---------------- fused MLP: hidden = relu(X@W1+b1) in LDS, out = hidden@W2+b2 ----------------
__global__ __launch_bounds__(256) void mlp_fused(const unsigned short* __restrict__ H2,
                                                 const int* __restrict__ cat,
                                                 const unsigned short* __restrict__ W1T,
                                                 const float* __restrict__ b1,
                                                 const float* __restrict__ W2,
                                                 const float* __restrict__ b2,
                                                 float* __restrict__ out, int NCAT) {
    __shared__ float hidd[64][132];   // padded: bank = (nb*4 + d) % 32 -> 2-way max
    int t = threadIdx.x;
    int wv = t >> 6, l = t & 63;
    int l15 = l & 15, lq = l >> 4;
    int i = blockIdx.x * 64 + wv * 16 + l15;
    int iclamp = i < NCAT ? i : NCAT - 1;
    int node = cat[iclamp];

    short8 bfrag[8];
    const unsigned short* xrow = H2 + (size_t)node * (CCH * HID);
#pragma unroll
    for (int kk = 0; kk < 8; ++kk)
        bfrag[kk] = *(const short8*)(xrow + kk * 32 + lq * 8);

    int nb = wv * 16 + l15;   // node slot within block
#pragma unroll
    for (int mt = 0; mt < 8; ++mt) {
        floatx4 acc = {0.f, 0.f, 0.f, 0.f};
        const unsigned short* arow = W1T + (size_t)(mt * 16 + l15) * (CCH * HID);
#pragma unroll
        for (int kk = 0; kk < 8; ++kk) {
            short8 a = *(const short8*)(arow + kk * 32 + lq * 8);
            acc = __builtin_amdgcn_mfma_f32_16x16x32_bf16(a, bfrag[kk], acc, 0, 0, 0);
        }
        int d0 = mt * 16 + lq * 4;
#pragma unroll
        for (int r = 0; r < 4; ++r)
            hidd[nb][d0 + r] = fmaxf(acc[r] + b1[d0 + r], 0.f);
    }
    __syncthreads();

    // second layer: thread t -> node slot t>>2, classes (t&3)*4 .. +3
    int il = t >> 2;
    int cls0 = (t & 3) * 4;
    int i_out = blockIdx.x * 64 + il;
    if (i_out < NCAT) {
        float o0 = b2[cls0], o1 = b2[cls0 + 1], o2 = b2[cls0 + 2], o3 = b2[cls0 + 3];
        const float* hr = hidd[il];
#pragma unroll 8
        for (int j = 0; j < HID; ++j) {
            float hv = hr[j];
            const float* w2r = W2 + j * NCLS + cls0;
            o0 += hv * w2r[0];
            o1 += hv * w2r[1];
            o2 += hv * w2r[2];
            o3 += hv * w2r[3];
        }
        floatx4 o = {o0, o1, o2, o3};
        *(floatx4*)(out + (size_t)i_out * NCLS + cls0) = o;
    }
}

extern "C" void kernel_launch(void* const* d_in, const int* in_sizes, int n_in,
                              void* d_out, int out_size, void* d_ws, size_t ws_size,
                              hipStream_t stream) {
    const float* h    = (const float*)d_in[0];
    const int* src    = (const int*)d_in[1];
    const int* dst    = (const int*)d_in[2];
    const int* etype  = (const int*)d_in[3];
    const int* cat    = (const int*)d_in[4];
    const float* gt_w = (const float*)d_in[5];
    const float* Wc   = (const float*)d_in[6];
    const float* W1   = (const float*)d_in[7];
    const float* b1   = (const float*)d_in[8];
    const float* W2   = (const float*)d_in[9];
    const float* b2   = (const float*)d_in[10];
    float* out = (float*)d_out;

    const int N = in_sizes[0] / IN_DIM;   // 50000
    const int E = in_sizes[1];            // 500000
    const int NCAT = in_sizes[4];         // 10000
    const int NCHUNK = (N + 255) / 256;

    char* p = (char*)d_ws;
    auto alloc = [&](size_t bytes) {
        char* q = p;
        p += (bytes + 255) & ~(size_t)255;
        return q;
    };
    unsigned short* HA   = (unsigned short*)alloc((size_t)N * CCH * HID * 2);
    unsigned short* HB   = (unsigned short*)alloc((size_t)N * CCH * HID * 2);
    unsigned short* WcT  = (unsigned short*)alloc((size_t)CCH * HID * IN_DIM * 2);
    unsigned short* W1T  = (unsigned short*)alloc((size_t)HID * CCH * HID * 2);
    int*   counts        = (int*)alloc((size_t)N * 4);
    int*   offsets       = (int*)alloc((size_t)(N + 1) * 4);
    int*   cursor        = (int*)alloc((size_t)N * 4);
    int*   partials      = (int*)alloc((size_t)NCHUNK * 4);
    int*   chunk_off     = (int*)alloc((size_t)NCHUNK * 4);
    int2*  epack         = (int2*)alloc((size_t)E * 8);
    float* filt          = (float*)alloc((size_t)LL * CCH * RR * 4);

    hipMemsetAsync(counts, 0, (size_t)N * 4, stream);

    cvt_weights<<<(CCH * HID * IN_DIM + 255) / 256, 256, 0, stream>>>(Wc, W1, gt_w, WcT, W1T, filt);
    proj_mfma<<<(N + 63) / 64, 256, 0, stream>>>(h, WcT, HA, N);

    count_kernel<<<512, 256, 0, stream>>>(dst, counts, E);
    scanA_kernel<<<NCHUNK, 256, 0, stream>>>(counts, partials, N);
    scanB_kernel<<<1, 256, 0, stream>>>(partials, chunk_off, NCHUNK);
    scanC_kernel<<<NCHUNK, 256, 0, stream>>>(counts, chunk_off, offsets, cursor, N);
    fill_kernel<<<512, 256, 0, stream>>>(src, dst, etype, cursor, epack, E);

    agg_kernel<<<(N + 7) / 8, 256, 0, stream>>>((const uint4*)HA, (uint4*)HB,
                                                offsets, epack, filt, N);
    agg_kernel<<<(N + 7) / 8, 256, 0, stream>>>((const uint4*)HB, (uint4*)HA,
                                                offsets, epack, filt + CCH * RR, N);

    mlp_fused<<<(NCAT + 63) / 64, 256, 0, stream>>>(HA, cat, W1T, b1, W2, b2, out, NCAT);
}

// Round 12
// 285.814 us; speedup vs baseline: 1.2735x; 1.0168x over previous
//
#include <hip/hip_runtime.h>
#include <hip/hip_bf16.h>

#define IN_DIM 256
#define HID 128
#define CCH 2
#define RR 5
#define LL 2
#define NCLS 16

typedef __attribute__((ext_vector_type(8))) short short8;
typedef __attribute__((ext_vector_type(4))) short short4_;
typedef __attribute__((ext_vector_type(4))) float floatx4;

__device__ __forceinline__ unsigned short f2bf(float f) {
    unsigned int u = __float_as_uint(f);
    unsigned int r = (u + 0x7FFFu + ((u >> 16) & 1u)) >> 16;   // RN-even
    return (unsigned short)r;
}

// ---------------- fused: Filt softmax + fragment-major weight conversion ----------------
// WcFrag[((mt*8+kk)*64 + l)*8 + j] = bf16(Wc[c][k][d]),  m=mt*16+(l&15), c=m>>7, d=m&127,
//   k = kk*32 + (l>>4)*8 + j.  -> per-(mt,kk) the 64 lanes' 16B frags are contiguous (1KB).
__global__ void cvt_weights(const float* __restrict__ Wc, const float* __restrict__ W1,
                            const float* __restrict__ gt_w,
                            unsigned short* __restrict__ WcFrag, unsigned short* __restrict__ W1Frag,
                            float* __restrict__ filt) {
    int t = blockIdx.x * 256 + threadIdx.x;
    if (blockIdx.x == 0 && threadIdx.x < LL * CCH) {
        const float* g = gt_w + threadIdx.x * RR;
        float m = -1e30f;
        for (int r = 0; r < RR; ++r) m = fmaxf(m, g[r]);
        float e[RR], s = 0.f;
        for (int r = 0; r < RR; ++r) { e[r] = __expf(g[r] - m); s += e[r]; }
        for (int r = 0; r < RR; ++r) filt[threadIdx.x * RR + r] = e[r] / s;
    }
    if (t < 8192) {                      // Wc fragments: 16mt x 8kk x 64 lanes
        int fid = t;
        int mt = fid >> 9;
        int kk = (fid >> 6) & 7;
        int l = fid & 63;
        int l15 = l & 15, lq = l >> 4;
        int m = mt * 16 + l15;
        int c = m >> 7, d = m & 127;
        int k0 = kk * 32 + lq * 8;
        unsigned short* dstp = WcFrag + (size_t)fid * 8;
#pragma unroll
        for (int j = 0; j < 8; ++j)
            dstp[j] = f2bf(Wc[((size_t)c * IN_DIM + k0 + j) * HID + d]);
    } else if (t < 12288) {              // W1 fragments: 8mt x 8kk x 64 lanes
        int fid = t - 8192;
        int mt = fid >> 9;
        int kk = (fid >> 6) & 7;
        int l = fid & 63;
        int l15 = l & 15, lq = l >> 4;
        int m = mt * 16 + l15;           // output dim 0..127
        int k0 = kk * 32 + lq * 8;
        unsigned short* dstp = W1Frag + (size_t)fid * 8;
#pragma unroll
        for (int j = 0; j < 8; ++j)
            dstp[j] = f2bf(W1[(size_t)(k0 + j) * HID + m]);
    }
}

// ---------------- Projection: LDS-staged B, coalesced fragment-major A ----------------
__global__ __launch_bounds__(256, 2) void proj_mfma(const float* __restrict__ h,
                                                    const unsigned short* __restrict__ WcFrag,
                                                    unsigned short* __restrict__ H0, int N) {
    __shared__ unsigned short Bl[64 * 256];   // 32 KB
    int t = threadIdx.x;
    int wv = t >> 6, l = t & 63;
    int l15 = l & 15, lq = l >> 4;
    int n0 = blockIdx.x * 64;

#pragma unroll
    for (int i = 0; i < 16; ++i) {
        int fi = t * 4 + i * 1024;
        int r = fi >> 8;
        int k = fi & 255;
        int node = n0 + r;
        const float* src = h + (size_t)(node < N ? node : N - 1) * IN_DIM + k;
        floatx4 f = *(const floatx4*)src;
        short4_ s4;
        s4[0] = (short)f2bf(f[0]); s4[1] = (short)f2bf(f[1]);
        s4[2] = (short)f2bf(f[2]); s4[3] = (short)f2bf(f[3]);
        int c = k >> 3;
        int half = (k >> 2) & 1;
        int cs = c ^ ((r & 7) << 2);
        *(short4_*)(&Bl[r * 256 + cs * 8 + half * 4]) = s4;
    }
    __syncthreads();

    floatx4 acc[4][4];
#pragma unroll
    for (int m = 0; m < 4; ++m)
#pragma unroll
        for (int n = 0; n < 4; ++n) acc[m][n] = (floatx4){0.f, 0.f, 0.f, 0.f};

#pragma unroll
    for (int kh = 0; kh < 2; ++kh) {
        short8 a[4][4];
#pragma unroll
        for (int mt0 = 0; mt0 < 4; ++mt0) {
#pragma unroll
            for (int kk = 0; kk < 4; ++kk)
                a[mt0][kk] = *(const short8*)(WcFrag +
                    (((size_t)(wv * 4 + mt0) * 8 + (kh * 4 + kk)) * 64 + l) * 8);
        }
#pragma unroll
        for (int nf = 0; nf < 4; ++nf) {
            int r = nf * 16 + l15;
            short8 b[4];
#pragma unroll
            for (int kk = 0; kk < 4; ++kk) {
                int c = (kh * 4 + kk) * 4 + lq;
                int cs = c ^ ((r & 7) << 2);
                b[kk] = *(const short8*)(&Bl[r * 256 + cs * 8]);
            }
#pragma unroll
            for (int mt0 = 0; mt0 < 4; ++mt0)
#pragma unroll
                for (int kk = 0; kk < 4; ++kk)
                    acc[mt0][nf] = __builtin_amdgcn_mfma_f32_16x16x32_bf16(a[mt0][kk], b[kk],
                                                                           acc[mt0][nf], 0, 0, 0);
        }
    }

#pragma unroll
    for (int mt0 = 0; mt0 < 4; ++mt0) {
        int m0 = (wv * 4 + mt0) * 16 + lq * 4;
#pragma unroll
        for (int nf = 0; nf < 4; ++nf) {
            int node = n0 + nf * 16 + l15;
            if (node < N) {
                short4_ st;
                st[0] = (short)f2bf(acc[mt0][nf][0]); st[1] = (short)f2bf(acc[mt0][nf][1]);
                st[2] = (short)f2bf(acc[mt0][nf][2]); st[3] = (short)f2bf(acc[mt0][nf][3]);
                *(short4_*)(H0 + (size_t)node * (CCH * HID) + m0) = st;
            }
        }
    }
}

// ---------------- CSR build ----------------
__global__ void count_kernel(const int* __restrict__ dst, int* __restrict__ counts, int E) {
    for (int e = blockIdx.x * blockDim.x + threadIdx.x; e < E; e += gridDim.x * blockDim.x)
        atomicAdd(&counts[dst[e]], 1);
}

__global__ void scanA_kernel(const int* __restrict__ counts, int* __restrict__ partials, int n) {
    __shared__ int s[256];
    int t = threadIdx.x;
    int i = blockIdx.x * 256 + t;
    int v = (i < n) ? counts[i] : 0;
    s[t] = v;
    __syncthreads();
    for (int off = 1; off < 256; off <<= 1) {
        int tv = (t >= off) ? s[t - off] : 0;
        __syncthreads();
        s[t] += tv;
        __syncthreads();
    }
    if (t == 255) partials[blockIdx.x] = s[255];
}

__global__ void scanB_kernel(const int* __restrict__ partials, int* __restrict__ chunk_off, int nchunk) {
    __shared__ int s[256];
    int t = threadIdx.x;
    int v = (t < nchunk) ? partials[t] : 0;
    s[t] = v;
    __syncthreads();
    for (int off = 1; off < 256; off <<= 1) {
        int tv = (t >= off) ? s[t - off] : 0;
        __syncthreads();
        s[t] += tv;
        __syncthreads();
    }
    if (t < nchunk) chunk_off[t] = s[t] - v;   // exclusive
}

__global__ void scanC_kernel(const int* __restrict__ counts, const int* __restrict__ chunk_off,
                             int* __restrict__ offsets, int* __restrict__ cursor, int n) {
    __shared__ int s[256];
    int t = threadIdx.x;
    int i = blockIdx.x * 256 + t;
    int v = (i < n) ? counts[i] : 0;
    s[t] = v;
    __syncthreads();
    for (int off = 1; off < 256; off <<= 1) {
        int tv = (t >= off) ? s[t - off] : 0;
        __syncthreads();
        s[t] += tv;
        __syncthreads();
    }
    if (i < n) {
        int incl = chunk_off[blockIdx.x] + s[t];
        offsets[i + 1] = incl;
        cursor[i] = incl - v;
    }
    if (i == 0) offsets[0] = 0;
}

__global__ void fill_kernel(const int* __restrict__ src, const int* __restrict__ dst,
                            const int* __restrict__ etype, int* __restrict__ cursor,
                            int2* __restrict__ epack, int E) {
    for (int e = blockIdx.x * blockDim.x + threadIdx.x; e < E; e += gridDim.x * blockDim.x) {
        int d = dst[e];
        int p = atomicAdd(&cursor[d], 1);
        epack[p] = make_int2(src[e], etype[e]);
    }
}

// ---------------- Aggregation: 8 nodes/block, 32-lane group per node ----------------
#define GETSRC(dn, s_, e_) do {                                     \
    s_ = __shfl(ep.x, (dn) & 31, 32);                               \
    e_ = __shfl(ep.y, (dn) & 31, 32);                               \
    if ((dn) >= 32) { int2 _p = epack[e0 + (dn)]; s_ = _p.x; e_ = _p.y; } \
} while (0)

#define ACCUM(vv, ww) do {                                          \
    acc[0] += (ww) * __uint_as_float((vv).x << 16);                 \
    acc[1] += (ww) * __uint_as_float((vv).x & 0xFFFF0000u);         \
    acc[2] += (ww) * __uint_as_float((vv).y << 16);                 \
    acc[3] += (ww) * __uint_as_float((vv).y & 0xFFFF0000u);         \
    acc[4] += (ww) * __uint_as_float((vv).z << 16);                 \
    acc[5] += (ww) * __uint_as_float((vv).z & 0xFFFF0000u);         \
    acc[6] += (ww) * __uint_as_float((vv).w << 16);                 \
    acc[7] += (ww) * __uint_as_float((vv).w & 0xFFFF0000u);         \
} while (0)

__global__ __launch_bounds__(256) void agg_kernel(const uint4* __restrict__ Hin,
                                                  uint4* __restrict__ Hout,
                                                  const int* __restrict__ offs,
                                                  const int2* __restrict__ epack,
                                                  const float* __restrict__ filt, int N) {
    int t = threadIdx.x;
    int g = t >> 5;
    int lane32 = t & 31;
    int node = blockIdx.x * 8 + g;
    if (node >= N) return;
    int c = lane32 >> 4;
    float f0 = filt[c * RR + 0], f1 = filt[c * RR + 1], f2 = filt[c * RR + 2];
    float f3 = filt[c * RR + 3], f4 = filt[c * RR + 4];

    int e0 = offs[node], e1 = offs[node + 1];
    int deg = e1 - e0;
    int2 ep = epack[e0 + (lane32 < deg ? lane32 : deg - 1)];

    float acc[8];
#pragma unroll
    for (int r = 0; r < 8; ++r) acc[r] = 0.f;
    float dw = 0.f;

    uint4 va, vb;
    int eta = 0, etb = 0;
    { int s; GETSRC(0, s, eta); va = Hin[(size_t)s * 32 + lane32]; }
    if (deg > 1) { int s; GETSRC(1, s, etb); vb = Hin[(size_t)s * 32 + lane32]; }
    else vb = va;

    int d = 0;
    for (;;) {
        {
            float w = (eta == 0) ? f0 : (eta == 1) ? f1 : (eta == 2) ? f2 : (eta == 3) ? f3 : f4;
            dw += w;
            ACCUM(va, w);
        }
        int dn = d + 2;
        if (dn < deg) { int s; GETSRC(dn, s, eta); va = Hin[(size_t)s * 32 + lane32]; }
        ++d; if (d >= deg) break;
        {
            float w = (etb == 0) ? f0 : (etb == 1) ? f1 : (etb == 2) ? f2 : (etb == 3) ? f3 : f4;
            dw += w;
            ACCUM(vb, w);
        }
        dn = d + 2;
        if (dn < deg) { int s; GETSRC(dn, s, etb); vb = Hin[(size_t)s * 32 + lane32]; }
        ++d; if (d >= deg) break;
    }

    float inv = 1.f / dw;
    uint4 o;
    o.x = (unsigned int)f2bf(acc[0] * inv) | ((unsigned int)f2bf(acc[1] * inv) << 16);
    o.y = (unsigned int)f2bf(acc[2] * inv) | ((unsigned int)f2bf(acc[3] * inv) << 16);
    o.z = (unsigned int)f2bf(acc[4] * inv) | ((unsigned int)f2bf(acc[5] * inv) << 16);
    o.w = (unsigned int)f2bf(acc[6] * inv) | ((unsigned int)f2bf(acc[7] * inv) << 16);
    Hout[(size_t)node * 32 + lane32] = o;
}

// ---------------- fused MLP with fragment-major W1 ----------------
__global__ __launch_bounds__(256) void mlp_fused(const unsigned short* __restrict__ H2,
                                                 const int* __restrict__ cat,
                                                 const unsigned short* __restrict__ W1Frag,
                                                 const float* __restrict__ b1,
                                                 const float* __restrict__ W2,
                                                 const float* __restrict__ b2,
                                                 float* __restrict__ out, int NCAT) {
    __shared__ float hidd[64][132];
    int t = threadIdx.x;
    int wv = t >> 6, l = t & 63;
    int l15 = l & 15, lq = l >> 4;
    int i = blockIdx.x * 64 + wv * 16 + l15;
    int iclamp = i < NCAT ? i : NCAT - 1;
    int node = cat[iclamp];

    short8 bfrag[8];
    const unsigned short* xrow = H2 + (size_t)node * (CCH * HID);
#pragma unroll
    for (int kk = 0; kk < 8; ++kk)
        bfrag[kk] = *(const short8*)(xrow + kk * 32 + lq * 8);

    int nb = wv * 16 + l15;
#pragma unroll
    for (int mt = 0; mt < 8; ++mt) {
        floatx4 acc = {0.f, 0.f, 0.f, 0.f};
#pragma unroll
        for (int kk = 0; kk < 8; ++kk) {
            short8 a = *(const short8*)(W1Frag + (((size_t)mt * 8 + kk) * 64 + l) * 8);
            acc = __builtin_amdgcn_mfma_f32_16x16x32_bf16(a, bfrag[kk], acc, 0, 0, 0);
        }
        int d0 = mt * 16 + lq * 4;
#pragma unroll
        for (int r = 0; r < 4; ++r)
            hidd[nb][d0 + r] = fmaxf(acc[r] + b1[d0 + r], 0.f);
    }
    __syncthreads();

    int il = t >> 2;
    int cls0 = (t & 3) * 4;
    int i_out = blockIdx.x * 64 + il;
    if (i_out < NCAT) {
        float o0 = b2[cls0], o1 = b2[cls0 + 1], o2 = b2[cls0 + 2], o3 = b2[cls0 + 3];
        const float* hr = hidd[il];
#pragma unroll 8
        for (int j = 0; j < HID; ++j) {
            float hv = hr[j];
            const float* w2r = W2 + j * NCLS + cls0;
            o0 += hv * w2r[0];
            o1 += hv * w2r[1];
            o2 += hv * w2r[2];
            o3 += hv * w2r[3];
        }
        floatx4 o = {o0, o1, o2, o3};
        *(floatx4*)(out + (size_t)i_out * NCLS + cls0) = o;
    }
}

extern "C" void kernel_launch(void* const* d_in, const int* in_sizes, int n_in,
                              void* d_out, int out_size, void* d_ws, size_t ws_size,
                              hipStream_t stream) {
    const float* h    = (const float*)d_in[0];
    const int* src    = (const int*)d_in[1];
    const int* dst    = (const int*)d_in[2];
    const int* etype  = (const int*)d_in[3];
    const int* cat    = (const int*)d_in[4];
    const float* gt_w = (const float*)d_in[5];
    const float* Wc   = (const float*)d_in[6];
    const float* W1   = (const float*)d_in[7];
    const float* b1   = (const float*)d_in[8];
    const float* W2   = (const float*)d_in[9];
    const float* b2   = (const float*)d_in[10];
    float* out = (float*)d_out;

    const int N = in_sizes[0] / IN_DIM;   // 50000
    const int E = in_sizes[1];            // 500000
    const int NCAT = in_sizes[4];         // 10000
    const int NCHUNK = (N + 255) / 256;

    char* p = (char*)d_ws;
    auto alloc = [&](size_t bytes) {
        char* q = p;
        p += (bytes + 255) & ~(size_t)255;
        return q;
    };
    unsigned short* HA     = (unsigned short*)alloc((size_t)N * CCH * HID * 2);
    unsigned short* HB     = (unsigned short*)alloc((size_t)N * CCH * HID * 2);
    unsigned short* WcFrag = (unsigned short*)alloc((size_t)CCH * HID * IN_DIM * 2);
    unsigned short* W1Frag = (unsigned short*)alloc((size_t)HID * CCH * HID * 2);
    int*   counts          = (int*)alloc((size_t)N * 4);
    int*   offsets         = (int*)alloc((size_t)(N + 1) * 4);
    int*   cursor          = (int*)alloc((size_t)N * 4);
    int*   partials        = (int*)alloc((size_t)NCHUNK * 4);
    int*   chunk_off       = (int*)alloc((size_t)NCHUNK * 4);
    int2*  epack           = (int2*)alloc((size_t)E * 8);
    float* filt            = (float*)alloc((size_t)LL * CCH * RR * 4);

    hipMemsetAsync(counts, 0, (size_t)N * 4, stream);

    cvt_weights<<<48, 256, 0, stream>>>(Wc, W1, gt_w, WcFrag, W1Frag, filt);
    proj_mfma<<<(N + 63) / 64, 256, 0, stream>>>(h, WcFrag, HA, N);

    count_kernel<<<512, 256, 0, stream>>>(dst, counts, E);
    scanA_kernel<<<NCHUNK, 256, 0, stream>>>(counts, partials, N);
    scanB_kernel<<<1, 256, 0, stream>>>(partials, chunk_off, NCHUNK);
    scanC_kernel<<<NCHUNK, 256, 0, stream>>>(counts, chunk_off, offsets, cursor, N);
    fill_kernel<<<512, 256, 0, stream>>>(src, dst, etype, cursor, epack, E);

    agg_kernel<<<(N + 7) / 8, 256, 0, stream>>>((const uint4*)HA, (uint4*)HB,
                                                offsets, epack, filt, N);
    agg_kernel<<<(N + 7) / 8, 256, 0, stream>>>((const uint4*)HB, (uint4*)HA,
                                                offsets, epack, filt + CCH * RR, N);

    mlp_fused<<<(NCAT + 63) / 64, 256, 0, stream>>>(HA, cat, W1Frag, b1, W2, b2, out, NCAT);
}